// Round 1
// baseline (1002.723 us; speedup 1.0000x reference)
//
#include <hip/hip_runtime.h>
#include <hip/hip_bf16.h>

#define T_TOK   16384
#define DDIM    2048
#define HDIM    4096
#define NEXP    8
#define BM      128
#define BN      128
#define BK      32
#define LDS_STRIDE 56     // elems; 112B row stride = 7 quads -> conflict-free b128 frag reads
#define MAX_TILES 144

typedef __attribute__((ext_vector_type(4))) float f32x4;
typedef __attribute__((ext_vector_type(8))) __bf16 bf16x8;
typedef __attribute__((ext_vector_type(4))) __bf16 bf16x4;

// ws layout (int32 words):
// [0]                      n_tiles
// [16 .. 16+MT)            tile_expert
// [16+MT .. 16+2MT)        tile_row_start (offset into row_ids)
// [16+2MT .. 16+3MT)       tile_nrows
// [1024 .. 1024+T)         row_ids (slot indices sorted by expert)
#define WS_TILE_EXPERT 16
#define WS_TILE_START  (16 + MAX_TILES)
#define WS_TILE_NROWS  (16 + 2*MAX_TILES)
#define WS_ROW_IDS     1024

__global__ void routing_kernel(const int* __restrict__ topk_ids, int* __restrict__ wsi) {
    __shared__ int cnt[NEXP];
    __shared__ int base[NEXP];
    int tid = threadIdx.x;
    if (tid < NEXP) cnt[tid] = 0;
    __syncthreads();
    for (int i = tid; i < T_TOK; i += blockDim.x)
        atomicAdd(&cnt[topk_ids[i]], 1);
    __syncthreads();
    if (tid == 0) {
        int acc = 0, nt = 0;
        for (int e = 0; e < NEXP; ++e) {
            base[e] = acc;
            int c = cnt[e];
            for (int off = 0; off < c; off += BM) {
                wsi[WS_TILE_EXPERT + nt] = e;
                wsi[WS_TILE_START + nt]  = acc + off;
                wsi[WS_TILE_NROWS + nt]  = (c - off < BM) ? (c - off) : BM;
                nt++;
            }
            acc += c;
        }
        wsi[0] = nt;
    }
    __syncthreads();
    if (tid < NEXP) cnt[tid] = base[tid];
    __syncthreads();
    for (int i = tid; i < T_TOK; i += blockDim.x) {
        int pos = atomicAdd(&cnt[topk_ids[i]], 1);
        wsi[WS_ROW_IDS + pos] = i;
    }
}

__global__ __launch_bounds__(256, 2)
void grouped_gemm_kernel(const float* __restrict__ X,
                         const float* __restrict__ W,
                         const float* __restrict__ topk_weight,
                         const int* __restrict__ wsi,
                         float* __restrict__ Out) {
    const int tile = blockIdx.x;
    if (tile >= wsi[0]) return;
    const int e      = wsi[WS_TILE_EXPERT + tile];
    const int rstart = wsi[WS_TILE_START + tile];
    const int nrows  = wsi[WS_TILE_NROWS + tile];
    const int n0     = blockIdx.y * BN;
    const int* row_ids = wsi + WS_ROW_IDS;

    __shared__ __bf16 Asm[BM][LDS_STRIDE];
    __shared__ __bf16 Bsm[BN][LDS_STRIDE];   // B transposed: [col][k]

    const int t    = threadIdx.x;
    const int lane = t & 63;
    const int wid  = t >> 6;
    const int wm   = wid >> 1;   // 0..1
    const int wn   = wid & 1;    // 0..1
    const int r16  = lane & 15;
    const int c16  = lane >> 4;  // 0..3 (k-chunk of 8)

    // A staging assignment: 2 threads per row, 16 floats each
    const int arow  = t >> 1;
    const int ahalf = t & 1;
    const int aslot = (arow < nrows) ? row_ids[rstart + arow] : -1;
    const float* aptr = (aslot >= 0) ? (X + (size_t)aslot * DDIM + ahalf * 16) : X;

    // B staging assignment: sc = col lane, sk4 = k-block of 4 rows
    const int sc  = t & 31;
    const int sk4 = t >> 5;      // 0..7
    const float* wbase = W + (size_t)e * DDIM * HDIM + (size_t)(sk4 * 4) * HDIM + n0 + sc;

    f32x4 acc[4][4];
    #pragma unroll
    for (int i = 0; i < 4; ++i)
        #pragma unroll
        for (int j = 0; j < 4; ++j)
            acc[i][j] = (f32x4)(0.0f);

    for (int k0 = 0; k0 < DDIM; k0 += BK) {
        // ---- stage A (gathered x rows, f32 -> bf16)
        {
            bf16x8 v0, v1;
            if (aslot >= 0) {
                const float4* p = reinterpret_cast<const float4*>(aptr + k0);
                float4 f0 = p[0], f1 = p[1], f2 = p[2], f3 = p[3];
                v0[0]=(__bf16)f0.x; v0[1]=(__bf16)f0.y; v0[2]=(__bf16)f0.z; v0[3]=(__bf16)f0.w;
                v0[4]=(__bf16)f1.x; v0[5]=(__bf16)f1.y; v0[6]=(__bf16)f1.z; v0[7]=(__bf16)f1.w;
                v1[0]=(__bf16)f2.x; v1[1]=(__bf16)f2.y; v1[2]=(__bf16)f2.z; v1[3]=(__bf16)f2.w;
                v1[4]=(__bf16)f3.x; v1[5]=(__bf16)f3.y; v1[6]=(__bf16)f3.z; v1[7]=(__bf16)f3.w;
            } else {
                #pragma unroll
                for (int j = 0; j < 8; ++j) { v0[j] = (__bf16)0.0f; v1[j] = (__bf16)0.0f; }
            }
            *reinterpret_cast<bf16x8*>(&Asm[arow][ahalf * 16])     = v0;
            *reinterpret_cast<bf16x8*>(&Asm[arow][ahalf * 16 + 8]) = v1;
        }
        // ---- stage B (w tile, f32 -> bf16, transposed into [col][k])
        {
            const float* bp = wbase + (size_t)k0 * HDIM;
            float vals[4][4];
            #pragma unroll
            for (int kk = 0; kk < 4; ++kk)
                #pragma unroll
                for (int i = 0; i < 4; ++i)
                    vals[kk][i] = bp[(size_t)kk * HDIM + i * 32];
            #pragma unroll
            for (int i = 0; i < 4; ++i) {
                bf16x4 v;
                v[0] = (__bf16)vals[0][i];
                v[1] = (__bf16)vals[1][i];
                v[2] = (__bf16)vals[2][i];
                v[3] = (__bf16)vals[3][i];
                *reinterpret_cast<bf16x4*>(&Bsm[sc + 32 * i][sk4 * 4]) = v;
            }
        }
        __syncthreads();

        // ---- MFMA
        bf16x8 afr[4], bfr[4];
        #pragma unroll
        for (int mf = 0; mf < 4; ++mf)
            afr[mf] = *reinterpret_cast<const bf16x8*>(&Asm[wm * 64 + mf * 16 + r16][c16 * 8]);
        #pragma unroll
        for (int nf = 0; nf < 4; ++nf)
            bfr[nf] = *reinterpret_cast<const bf16x8*>(&Bsm[wn * 64 + nf * 16 + r16][c16 * 8]);
        #pragma unroll
        for (int mf = 0; mf < 4; ++mf)
            #pragma unroll
            for (int nf = 0; nf < 4; ++nf)
                acc[mf][nf] = __builtin_amdgcn_mfma_f32_16x16x32_bf16(afr[mf], bfr[nf], acc[mf][nf], 0, 0, 0);
        __syncthreads();
    }

    // ---- epilogue: weighted atomic scatter-add into token rows
    const int col0 = n0 + wn * 64;
    #pragma unroll
    for (int mf = 0; mf < 4; ++mf) {
        #pragma unroll
        for (int i = 0; i < 4; ++i) {
            int rl = wm * 64 + mf * 16 + c16 * 4 + i;
            if (rl < nrows) {
                int slot = row_ids[rstart + rl];
                float wt = topk_weight[slot];
                float* orow = Out + (size_t)(slot >> 1) * HDIM;
                #pragma unroll
                for (int nf = 0; nf < 4; ++nf)
                    atomicAdd(&orow[col0 + nf * 16 + r16], acc[mf][nf][i] * wt);
            }
        }
    }
}

extern "C" void kernel_launch(void* const* d_in, const int* in_sizes, int n_in,
                              void* d_out, int out_size, void* d_ws, size_t ws_size,
                              hipStream_t stream) {
    const float* X   = (const float*)d_in[0];
    const float* W   = (const float*)d_in[1];
    const float* wgt = (const float*)d_in[2];
    const int*   ids = (const int*)d_in[3];
    float* Out = (float*)d_out;
    int*   wsi = (int*)d_ws;

    hipMemsetAsync(d_out, 0, (size_t)out_size * sizeof(float), stream);
    routing_kernel<<<1, 256, 0, stream>>>(ids, wsi);
    dim3 grid(MAX_TILES, HDIM / BN, 1);
    grouped_gemm_kernel<<<grid, 256, 0, stream>>>(X, W, wgt, wsi, Out);
}

// Round 2
// 672.862 us; speedup vs baseline: 1.4902x; 1.4902x over previous
//
#include <hip/hip_runtime.h>
#include <hip/hip_bf16.h>

#define T_TOK   16384
#define DDIM    2048
#define HDIM    4096
#define NEXP    8
#define BM      128
#define BN      128
#define BK      32
#define MAX_TILES 144
#define TILEB   8192          // one BMxBK (or BNxBK) bf16 tile in bytes
#define NK      (DDIM / BK)   // 64 K-steps
#define NBAND   (HDIM / BN)   // 32 N-bands

typedef __attribute__((ext_vector_type(4))) float f32x4;
typedef __attribute__((ext_vector_type(8))) __bf16 bf16x8;
typedef __attribute__((ext_vector_type(4))) __bf16 bf16x4;

// ---- workspace layout ----
// ints (words):
#define WS_TILE_EXPERT 16
#define WS_TILE_START  (16 + MAX_TILES)
#define WS_TILE_NROWS  (16 + 2*MAX_TILES)
#define WS_ROW_IDS     1024
// bytes:
#define WS_APACK_OFF   131072ULL
#define WS_APACK_SZ    ((size_t)MAX_TILES * NK * TILEB)            // 75,497,472
#define WS_WB_OFF      (WS_APACK_OFF + WS_APACK_SZ)                // 75,628,544
#define WS_WB_SZ       ((size_t)NEXP * NBAND * NK * TILEB)         // 134,217,728
#define WS_FAST_NEED   (WS_WB_OFF + WS_WB_SZ)                      // 209,846,272

// swizzled byte position of element (row, k) inside an 8192B tile:
//   addr = row*64 + ((k*2) ^ ((row&3)<<4))
// 16-lane frag reads then hit every bank-quad with exactly 8 lanes -> conflict-free.

__device__ __forceinline__ void gload16(const void* g, void* l) {
    __builtin_amdgcn_global_load_lds(
        (const __attribute__((address_space(1))) void*)g,
        (__attribute__((address_space(3))) void*)l, 16, 0, 0);
}

__global__ void routing_kernel(const int* __restrict__ topk_ids, int* __restrict__ wsi) {
    __shared__ int cnt[NEXP];
    __shared__ int base[NEXP];
    int tid = threadIdx.x;
    if (tid < NEXP) cnt[tid] = 0;
    __syncthreads();
    for (int i = tid; i < T_TOK; i += blockDim.x)
        atomicAdd(&cnt[topk_ids[i]], 1);
    __syncthreads();
    if (tid == 0) {
        int acc = 0, nt = 0;
        for (int e = 0; e < NEXP; ++e) {
            base[e] = acc;
            int c = cnt[e];
            for (int off = 0; off < c; off += BM) {
                wsi[WS_TILE_EXPERT + nt] = e;
                wsi[WS_TILE_START + nt]  = acc + off;
                wsi[WS_TILE_NROWS + nt]  = (c - off < BM) ? (c - off) : BM;
                nt++;
            }
            acc += c;
        }
        wsi[0] = nt;
    }
    __syncthreads();
    if (tid < NEXP) cnt[tid] = base[tid];
    __syncthreads();
    for (int i = tid; i < T_TOK; i += blockDim.x) {
        int pos = atomicAdd(&cnt[topk_ids[i]], 1);
        wsi[WS_ROW_IDS + pos] = i;
    }
}

// ---- pack W [E][D][H] f32 -> tiled swizzled bf16 [E][band][k0][TILEB] ----
__global__ __launch_bounds__(256)
void pack_w_kernel(const float* __restrict__ W, unsigned char* __restrict__ wb) {
    const long long total = (long long)NEXP * (DDIM / 8) * HDIM; // thread: 8 k-elems, 1 col
    for (long long u = (long long)blockIdx.x * 256 + threadIdx.x; u < total;
         u += (long long)gridDim.x * 256) {
        int n  = (int)(u % HDIM);
        long long v = u / HDIM;
        int kb = (int)(v % (DDIM / 8));      // k-block of 8
        int e  = (int)(v / (DDIM / 8));
        const float* src = W + ((size_t)e * DDIM + (size_t)kb * 8) * HDIM + n;
        bf16x8 h;
        #pragma unroll
        for (int j = 0; j < 8; ++j)
            h[j] = (__bf16)src[(size_t)j * HDIM];
        size_t tile = (size_t)(e * NBAND + (n >> 7)) * NK + (kb >> 2);
        int row   = n & 127;
        int kbyte = ((kb & 3) * 16) ^ ((row & 3) << 4);
        *reinterpret_cast<bf16x8*>(wb + tile * TILEB + row * 64 + kbyte) = h;
    }
}

// ---- pack A: gather sorted X rows -> tiled swizzled bf16 [tile][k0][TILEB] ----
__global__ __launch_bounds__(256)
void pack_a_kernel(const float* __restrict__ X, const int* __restrict__ wsi,
                   unsigned char* __restrict__ apack) {
    const int tile = blockIdx.x;
    if (tile >= wsi[0]) return;
    const int k0i = blockIdx.y;              // 0..NK-1
    const int rstart = wsi[WS_TILE_START + tile];
    const int nrows  = wsi[WS_TILE_NROWS + tile];
    const int t = threadIdx.x;
    const int r = t >> 1, khalf = t & 1;     // 2 threads/row, 16 k-elems each
    bf16x8 v0, v1;
    if (r < nrows) {
        int slot = wsi[WS_ROW_IDS + rstart + r];
        const float4* p = reinterpret_cast<const float4*>(
            X + (size_t)slot * DDIM + k0i * BK + khalf * 16);
        float4 f0 = p[0], f1 = p[1], f2 = p[2], f3 = p[3];
        v0[0]=(__bf16)f0.x; v0[1]=(__bf16)f0.y; v0[2]=(__bf16)f0.z; v0[3]=(__bf16)f0.w;
        v0[4]=(__bf16)f1.x; v0[5]=(__bf16)f1.y; v0[6]=(__bf16)f1.z; v0[7]=(__bf16)f1.w;
        v1[0]=(__bf16)f2.x; v1[1]=(__bf16)f2.y; v1[2]=(__bf16)f2.z; v1[3]=(__bf16)f2.w;
        v1[4]=(__bf16)f3.x; v1[5]=(__bf16)f3.y; v1[6]=(__bf16)f3.z; v1[7]=(__bf16)f3.w;
    } else {
        #pragma unroll
        for (int j = 0; j < 8; ++j) { v0[j] = (__bf16)0.0f; v1[j] = (__bf16)0.0f; }
    }
    unsigned char* dst = apack + ((size_t)tile * NK + k0i) * TILEB + r * 64;
    const int swz = (r & 3) << 4;
    *reinterpret_cast<bf16x8*>(dst + ((khalf * 32)      ^ swz)) = v0;
    *reinterpret_cast<bf16x8*>(dst + ((khalf * 32 + 16) ^ swz)) = v1;
}

// ---- dense grouped GEMM over packed operands ----
__global__ __launch_bounds__(256, 2)
void gemm_fast(const unsigned char* __restrict__ apack,
               const unsigned char* __restrict__ wb,
               const float* __restrict__ topk_weight,
               const int* __restrict__ wsi,
               float* __restrict__ Out) {
    // 1D grid MAX_TILES*NBAND = 4608; bijective XCD swizzle (4608 % 8 == 0)
    const int id  = blockIdx.x;
    const int swz = (id & 7) * (MAX_TILES * NBAND / 8) + (id >> 3);
    const int band = swz / MAX_TILES;
    const int tile = swz % MAX_TILES;
    if (tile >= wsi[0]) return;
    const int e      = wsi[WS_TILE_EXPERT + tile];
    const int rstart = wsi[WS_TILE_START + tile];
    const int nrows  = wsi[WS_TILE_NROWS + tile];

    __shared__ unsigned char smem[2 * TILEB];   // A [0,8192), B [8192,16384)

    const int t    = threadIdx.x;
    const int lane = t & 63;
    const int wid  = t >> 6;
    const int wm   = wid >> 1;
    const int wn   = wid & 1;
    const int r16  = lane & 15;
    const int c16  = lane >> 4;

    const unsigned char* ag = apack + (size_t)tile * NK * TILEB + t * 16;
    const unsigned char* bg = wb + (size_t)(e * NBAND + band) * NK * TILEB + t * 16;
    unsigned char* lA = smem + wid * 1024;           // wave-uniform dest bases
    unsigned char* lB = smem + TILEB + wid * 1024;

    f32x4 acc[4][4];
    #pragma unroll
    for (int i = 0; i < 4; ++i)
        #pragma unroll
        for (int j = 0; j < 4; ++j)
            acc[i][j] = (f32x4)(0.0f);

    const int fswz = (r16 & 3) << 4;   // frag-read swizzle term (const per lane)
    const int koffA = (c16 * 16) ^ fswz;

    for (int k0 = 0; k0 < NK; ++k0) {
        gload16(ag,        lA);
        gload16(ag + 4096, lA + 4096);
        gload16(bg,        lB);
        gload16(bg + 4096, lB + 4096);
        ag += TILEB; bg += TILEB;
        __syncthreads();    // drains vmcnt + barrier

        bf16x8 afr[4], bfr[4];
        #pragma unroll
        for (int mf = 0; mf < 4; ++mf) {
            int row = wm * 64 + mf * 16 + r16;
            afr[mf] = *reinterpret_cast<const bf16x8*>(smem + row * 64 + koffA);
        }
        #pragma unroll
        for (int nf = 0; nf < 4; ++nf) {
            int row = wn * 64 + nf * 16 + r16;
            bfr[nf] = *reinterpret_cast<const bf16x8*>(smem + TILEB + row * 64 + koffA);
        }
        #pragma unroll
        for (int mf = 0; mf < 4; ++mf)
            #pragma unroll
            for (int nf = 0; nf < 4; ++nf)
                acc[mf][nf] = __builtin_amdgcn_mfma_f32_16x16x32_bf16(afr[mf], bfr[nf], acc[mf][nf], 0, 0, 0);
        __syncthreads();
    }

    // epilogue: weighted atomic scatter-add (each out element gets exactly 2 adds)
    const int col0 = band * BN + wn * 64;
    #pragma unroll
    for (int mf = 0; mf < 4; ++mf) {
        #pragma unroll
        for (int i = 0; i < 4; ++i) {
            int rl = wm * 64 + mf * 16 + c16 * 4 + i;
            if (rl < nrows) {
                int slot = wsi[WS_ROW_IDS + rstart + rl];
                float wt = topk_weight[slot];
                float* orow = Out + (size_t)(slot >> 1) * HDIM;
                #pragma unroll
                for (int nf = 0; nf < 4; ++nf)
                    atomicAdd(&orow[col0 + nf * 16 + r16], acc[mf][nf][i] * wt);
            }
        }
    }
}

// ================= fallback (verified round-1 kernel) =================
#define LDS_STRIDE 56
__global__ __launch_bounds__(256, 2)
void grouped_gemm_fallback(const float* __restrict__ X,
                           const float* __restrict__ W,
                           const float* __restrict__ topk_weight,
                           const int* __restrict__ wsi,
                           float* __restrict__ Out) {
    const int tile = blockIdx.x;
    if (tile >= wsi[0]) return;
    const int e      = wsi[WS_TILE_EXPERT + tile];
    const int rstart = wsi[WS_TILE_START + tile];
    const int nrows  = wsi[WS_TILE_NROWS + tile];
    const int n0     = blockIdx.y * BN;
    const int* row_ids = wsi + WS_ROW_IDS;

    __shared__ __bf16 Asm[BM][LDS_STRIDE];
    __shared__ __bf16 Bsm[BN][LDS_STRIDE];

    const int t    = threadIdx.x;
    const int lane = t & 63;
    const int wid  = t >> 6;
    const int wm   = wid >> 1;
    const int wn   = wid & 1;
    const int r16  = lane & 15;
    const int c16  = lane >> 4;

    const int arow  = t >> 1;
    const int ahalf = t & 1;
    const int aslot = (arow < nrows) ? row_ids[rstart + arow] : -1;
    const float* aptr = (aslot >= 0) ? (X + (size_t)aslot * DDIM + ahalf * 16) : X;

    const int sc  = t & 31;
    const int sk4 = t >> 5;
    const float* wbase = W + (size_t)e * DDIM * HDIM + (size_t)(sk4 * 4) * HDIM + n0 + sc;

    f32x4 acc[4][4];
    #pragma unroll
    for (int i = 0; i < 4; ++i)
        #pragma unroll
        for (int j = 0; j < 4; ++j)
            acc[i][j] = (f32x4)(0.0f);

    for (int k0 = 0; k0 < DDIM; k0 += BK) {
        {
            bf16x8 v0, v1;
            if (aslot >= 0) {
                const float4* p = reinterpret_cast<const float4*>(aptr + k0);
                float4 f0 = p[0], f1 = p[1], f2 = p[2], f3 = p[3];
                v0[0]=(__bf16)f0.x; v0[1]=(__bf16)f0.y; v0[2]=(__bf16)f0.z; v0[3]=(__bf16)f0.w;
                v0[4]=(__bf16)f1.x; v0[5]=(__bf16)f1.y; v0[6]=(__bf16)f1.z; v0[7]=(__bf16)f1.w;
                v1[0]=(__bf16)f2.x; v1[1]=(__bf16)f2.y; v1[2]=(__bf16)f2.z; v1[3]=(__bf16)f2.w;
                v1[4]=(__bf16)f3.x; v1[5]=(__bf16)f3.y; v1[6]=(__bf16)f3.z; v1[7]=(__bf16)f3.w;
            } else {
                #pragma unroll
                for (int j = 0; j < 8; ++j) { v0[j] = (__bf16)0.0f; v1[j] = (__bf16)0.0f; }
            }
            *reinterpret_cast<bf16x8*>(&Asm[arow][ahalf * 16])     = v0;
            *reinterpret_cast<bf16x8*>(&Asm[arow][ahalf * 16 + 8]) = v1;
        }
        {
            const float* bp = wbase + (size_t)k0 * HDIM;
            float vals[4][4];
            #pragma unroll
            for (int kk = 0; kk < 4; ++kk)
                #pragma unroll
                for (int i = 0; i < 4; ++i)
                    vals[kk][i] = bp[(size_t)kk * HDIM + i * 32];
            #pragma unroll
            for (int i = 0; i < 4; ++i) {
                bf16x4 v;
                v[0] = (__bf16)vals[0][i];
                v[1] = (__bf16)vals[1][i];
                v[2] = (__bf16)vals[2][i];
                v[3] = (__bf16)vals[3][i];
                *reinterpret_cast<bf16x4*>(&Bsm[sc + 32 * i][sk4 * 4]) = v;
            }
        }
        __syncthreads();

        bf16x8 afr[4], bfr[4];
        #pragma unroll
        for (int mf = 0; mf < 4; ++mf)
            afr[mf] = *reinterpret_cast<const bf16x8*>(&Asm[wm * 64 + mf * 16 + r16][c16 * 8]);
        #pragma unroll
        for (int nf = 0; nf < 4; ++nf)
            bfr[nf] = *reinterpret_cast<const bf16x8*>(&Bsm[wn * 64 + nf * 16 + r16][c16 * 8]);
        #pragma unroll
        for (int mf = 0; mf < 4; ++mf)
            #pragma unroll
            for (int nf = 0; nf < 4; ++nf)
                acc[mf][nf] = __builtin_amdgcn_mfma_f32_16x16x32_bf16(afr[mf], bfr[nf], acc[mf][nf], 0, 0, 0);
        __syncthreads();
    }

    const int col0 = n0 + wn * 64;
    #pragma unroll
    for (int mf = 0; mf < 4; ++mf) {
        #pragma unroll
        for (int i = 0; i < 4; ++i) {
            int rl = wm * 64 + mf * 16 + c16 * 4 + i;
            if (rl < nrows) {
                int slot = row_ids[rstart + rl];
                float wt = topk_weight[slot];
                float* orow = Out + (size_t)(slot >> 1) * HDIM;
                #pragma unroll
                for (int nf = 0; nf < 4; ++nf)
                    atomicAdd(&orow[col0 + nf * 16 + r16], acc[mf][nf][i] * wt);
            }
        }
    }
}

extern "C" void kernel_launch(void* const* d_in, const int* in_sizes, int n_in,
                              void* d_out, int out_size, void* d_ws, size_t ws_size,
                              hipStream_t stream) {
    const float* X   = (const float*)d_in[0];
    const float* W   = (const float*)d_in[1];
    const float* wgt = (const float*)d_in[2];
    const int*   ids = (const int*)d_in[3];
    float* Out = (float*)d_out;
    int*   wsi = (int*)d_ws;

    hipMemsetAsync(d_out, 0, (size_t)out_size * sizeof(float), stream);
    routing_kernel<<<1, 256, 0, stream>>>(ids, wsi);

    if (ws_size >= WS_FAST_NEED) {
        unsigned char* apack = (unsigned char*)d_ws + WS_APACK_OFF;
        unsigned char* wb    = (unsigned char*)d_ws + WS_WB_OFF;
        pack_w_kernel<<<8192, 256, 0, stream>>>(W, wb);
        dim3 agrid(MAX_TILES, NK, 1);
        pack_a_kernel<<<agrid, 256, 0, stream>>>(X, wsi, apack);
        gemm_fast<<<MAX_TILES * NBAND, 256, 0, stream>>>(apack, wb, wgt, wsi, Out);
    } else {
        dim3 grid(MAX_TILES, NBAND, 1);
        grouped_gemm_fallback<<<grid, 256, 0, stream>>>(X, W, wgt, wsi, Out);
    }
}

// Round 3
// 654.952 us; speedup vs baseline: 1.5310x; 1.0273x over previous
//
#include <hip/hip_runtime.h>
#include <hip/hip_bf16.h>

#define T_TOK   16384
#define DDIM    2048
#define HDIM    4096
#define NEXP    8
#define BM      256
#define BN      256
#define BK      32
#define NKT     (DDIM / BK)     // 64 K-tiles
#define NBAND   (HDIM / BN)     // 16 N-bands
#define MAX_TILES 72            // worst case: 16384/256 + 7 = 71
#define KTILE_BYTES 16384       // 256 rows x 32 k x 2B (one A or B K-tile image)
#define NBLK    (MAX_TILES * NBAND)   // 1152, % 8 == 0

typedef __attribute__((ext_vector_type(4))) float f32x4;
typedef __attribute__((ext_vector_type(8))) __bf16 bf16x8;

// ---- workspace layout ----
#define WS_TILE_EXPERT 16
#define WS_TILE_START  (16 + MAX_TILES)
#define WS_TILE_NROWS  (16 + 2*MAX_TILES)
#define WS_ROW_IDS     1024
#define WS_APACK_OFF   131072ULL
#define WS_APACK_SZ    ((size_t)MAX_TILES * NKT * KTILE_BYTES)     // 75,497,472
#define WS_WB_OFF      (WS_APACK_OFF + WS_APACK_SZ)
#define WS_WB_SZ       ((size_t)NEXP * NBAND * NKT * KTILE_BYTES)  // 134,217,728

// Swizzle: element group q (k-elems q*8..q*8+8) of row r stored at 16B-quad
// position (q ^ ((r>>1)&3)) within the row's 64B. Any aligned 8-lane batch of
// a frag read then hits all 8 bank-quads of a 128B line-pair exactly once.

__device__ __forceinline__ void gload16(const void* g, void* l) {
    __builtin_amdgcn_global_load_lds(
        (const __attribute__((address_space(1))) void*)g,
        (__attribute__((address_space(3))) void*)l, 16, 0, 0);
}

__global__ void routing_kernel(const int* __restrict__ topk_ids, int* __restrict__ wsi) {
    __shared__ int cnt[NEXP];
    __shared__ int base[NEXP];
    int tid = threadIdx.x;
    if (tid < NEXP) cnt[tid] = 0;
    __syncthreads();
    for (int i = tid; i < T_TOK; i += blockDim.x)
        atomicAdd(&cnt[topk_ids[i]], 1);
    __syncthreads();
    if (tid == 0) {
        int acc = 0, nt = 0;
        for (int e = 0; e < NEXP; ++e) {
            base[e] = acc;
            int c = cnt[e];
            for (int off = 0; off < c; off += BM) {
                wsi[WS_TILE_EXPERT + nt] = e;
                wsi[WS_TILE_START + nt]  = acc + off;
                wsi[WS_TILE_NROWS + nt]  = (c - off < BM) ? (c - off) : BM;
                nt++;
            }
            acc += c;
        }
        wsi[0] = nt;
    }
    __syncthreads();
    if (tid < NEXP) cnt[tid] = base[tid];
    __syncthreads();
    for (int i = tid; i < T_TOK; i += blockDim.x) {
        int pos = atomicAdd(&cnt[topk_ids[i]], 1);
        wsi[WS_ROW_IDS + pos] = i;
    }
}

// ---- pack W [E][D][H] f32 -> [E][band][ktile][16KB swizzled image] bf16 ----
// thread handles one (e, ktile, col): 32 k-elems -> one full 64B row of image
__global__ __launch_bounds__(256)
void pack_w_kernel(const float* __restrict__ W, unsigned char* __restrict__ wb) {
    long long u = (long long)blockIdx.x * 256 + threadIdx.x; // NEXP*NKT*HDIM = 2,097,152
    int n  = (int)(u % HDIM);
    int kt = (int)((u / HDIM) % NKT);
    int e  = (int)(u / ((long long)HDIM * NKT));
    const float* src = W + ((size_t)e * DDIM + (size_t)kt * BK) * HDIM + n;
    int band = n >> 8;
    int row  = n & 255;
    unsigned char* dst = wb + (((size_t)(e * NBAND + band) * NKT + kt) * KTILE_BYTES) + row * 64;
    const int qsw = (row >> 1) & 3;
    #pragma unroll
    for (int q = 0; q < 4; ++q) {
        bf16x8 h;
        #pragma unroll
        for (int j = 0; j < 8; ++j)
            h[j] = (__bf16)src[(size_t)(q * 8 + j) * HDIM];
        *reinterpret_cast<bf16x8*>(dst + ((q ^ qsw) << 4)) = h;
    }
}

// ---- pack A: gather sorted X rows -> [tile][ktile][16KB swizzled image] ----
__global__ __launch_bounds__(256)
void pack_a_kernel(const float* __restrict__ X, const int* __restrict__ wsi,
                   unsigned char* __restrict__ apack) {
    const int tile = blockIdx.x;
    if (tile >= wsi[0]) return;
    const int kt = blockIdx.y;
    const int rstart = wsi[WS_TILE_START + tile];
    const int nrows  = wsi[WS_TILE_NROWS + tile];
    const int r = threadIdx.x;            // 0..255 = image row
    unsigned char* dst = apack + ((size_t)tile * NKT + kt) * KTILE_BYTES + r * 64;
    const int qsw = (r >> 1) & 3;
    bf16x8 v0, v1, v2, v3;
    if (r < nrows) {
        int slot = wsi[WS_ROW_IDS + rstart + r];
        const f32x4* p = reinterpret_cast<const f32x4*>(X + (size_t)slot * DDIM + kt * BK);
        f32x4 f[8];
        #pragma unroll
        for (int i = 0; i < 8; ++i) f[i] = p[i];
        #pragma unroll
        for (int j = 0; j < 4; ++j) { v0[j] = (__bf16)f[0][j]; v0[4+j] = (__bf16)f[1][j]; }
        #pragma unroll
        for (int j = 0; j < 4; ++j) { v1[j] = (__bf16)f[2][j]; v1[4+j] = (__bf16)f[3][j]; }
        #pragma unroll
        for (int j = 0; j < 4; ++j) { v2[j] = (__bf16)f[4][j]; v2[4+j] = (__bf16)f[5][j]; }
        #pragma unroll
        for (int j = 0; j < 4; ++j) { v3[j] = (__bf16)f[6][j]; v3[4+j] = (__bf16)f[7][j]; }
    } else {
        #pragma unroll
        for (int j = 0; j < 8; ++j) { v0[j]=(__bf16)0.f; v1[j]=(__bf16)0.f; v2[j]=(__bf16)0.f; v3[j]=(__bf16)0.f; }
    }
    *reinterpret_cast<bf16x8*>(dst + ((0 ^ qsw) << 4)) = v0;
    *reinterpret_cast<bf16x8*>(dst + ((1 ^ qsw) << 4)) = v1;
    *reinterpret_cast<bf16x8*>(dst + ((2 ^ qsw) << 4)) = v2;
    *reinterpret_cast<bf16x8*>(dst + ((3 ^ qsw) << 4)) = v3;
}

// ---- triple-buffered counted-vmcnt grouped GEMM, 256x256 tile, 8 waves ----
__device__ __forceinline__ void compute_ktile(const unsigned char* bufc,
                                              int abase, int bbase,
                                              f32x4 acc[8][4]) {
    bf16x8 afr[8], bfr[4];
    #pragma unroll
    for (int mf = 0; mf < 8; ++mf)
        afr[mf] = *reinterpret_cast<const bf16x8*>(bufc + abase + mf * 1024);
    #pragma unroll
    for (int nf = 0; nf < 4; ++nf)
        bfr[nf] = *reinterpret_cast<const bf16x8*>(bufc + bbase + nf * 1024);
    __builtin_amdgcn_s_setprio(1);
    #pragma unroll
    for (int mf = 0; mf < 8; ++mf)
        #pragma unroll
        for (int nf = 0; nf < 4; ++nf)
            acc[mf][nf] = __builtin_amdgcn_mfma_f32_16x16x32_bf16(afr[mf], bfr[nf], acc[mf][nf], 0, 0, 0);
    __builtin_amdgcn_s_setprio(0);
}

__global__ __launch_bounds__(512, 2)
void gemm_fast(const unsigned char* __restrict__ apack,
               const unsigned char* __restrict__ wb,
               const float* __restrict__ topk_weight,
               const int* __restrict__ wsi,
               float* __restrict__ Out) {
    const int id  = blockIdx.x;
    const int swz = (id & 7) * (NBLK / 8) + (id >> 3);   // bijective, 1152%8==0
    const int band = swz / MAX_TILES;                     // each XCD: 2 bands x all tiles
    const int tile = swz % MAX_TILES;
    if (tile >= wsi[0]) return;
    const int e      = wsi[WS_TILE_EXPERT + tile];
    const int rstart = wsi[WS_TILE_START + tile];
    const int nrows  = wsi[WS_TILE_NROWS + tile];

    extern __shared__ unsigned char smem[];   // 3 bufs x (A 16KB + B 16KB) = 96KB

    const int t    = threadIdx.x;
    const int lane = t & 63;
    const int wid  = t >> 6;     // 0..7
    const int wm   = wid >> 2;   // 0..1  (row half: 128 rows)
    const int wn   = wid & 3;    // 0..3  (col quarter: 64 cols)
    const int r16  = lane & 15;
    const int c16  = lane >> 4;  // k-quad selector

    const unsigned char* ag = apack + (size_t)tile * NKT * KTILE_BYTES + t * 16;
    const unsigned char* bg = wb + ((size_t)(e * NBAND + band) * NKT) * KTILE_BYTES + t * 16;
    const int ldst = wid * 1024;  // wave-uniform within each 8KB issue

    // per-lane frag-read bases (swizzle term constant across frags)
    const int qswz  = c16 ^ ((r16 >> 1) & 3);
    const int abase = (wm * 128 + r16) * 64 + (qswz << 4);
    const int bbase = 16384 + (wn * 64 + r16) * 64 + (qswz << 4);

    f32x4 acc[8][4];
    #pragma unroll
    for (int i = 0; i < 8; ++i)
        #pragma unroll
        for (int j = 0; j < 4; ++j)
            acc[i][j] = (f32x4)(0.0f);

#define STAGE(kt, boff) do {                                              \
    gload16(ag + (size_t)(kt) * KTILE_BYTES,         smem + (boff) + ldst);          \
    gload16(ag + (size_t)(kt) * KTILE_BYTES + 8192,  smem + (boff) + 8192 + ldst);   \
    gload16(bg + (size_t)(kt) * KTILE_BYTES,         smem + (boff) + 16384 + ldst);  \
    gload16(bg + (size_t)(kt) * KTILE_BYTES + 8192,  smem + (boff) + 24576 + ldst);  \
} while (0)

    // prologue: stage tiles 0,1; wait tile 0 (4 newest = tile 1 stay in flight)
    STAGE(0, 0);
    STAGE(1, 32768);
    asm volatile("s_waitcnt vmcnt(4)" ::: "memory");
    __builtin_amdgcn_s_barrier();
    __builtin_amdgcn_sched_barrier(0);

    int cb = 0;   // compute buffer, sb = (cb+2)%3 staging target
    #pragma unroll 1
    for (int kt = 0; kt < NKT - 2; ++kt) {
        int sb = cb + 2; if (sb >= 3) sb -= 3;
        STAGE(kt + 2, sb * 32768);
        compute_ktile(smem + cb * 32768, abase, bbase, acc);
        // tile kt+1's 4 loads (oldest outstanding) must land; keep tile kt+2's 4 in flight
        asm volatile("s_waitcnt vmcnt(4)" ::: "memory");
        __builtin_amdgcn_s_barrier();
        __builtin_amdgcn_sched_barrier(0);
        cb = (cb == 2) ? 0 : cb + 1;
    }
    // kt = NKT-2: nothing left to stage; drain tile NKT-1's loads
    compute_ktile(smem + cb * 32768, abase, bbase, acc);
    asm volatile("s_waitcnt vmcnt(0)" ::: "memory");
    __builtin_amdgcn_s_barrier();
    __builtin_amdgcn_sched_barrier(0);
    cb = (cb == 2) ? 0 : cb + 1;
    // kt = NKT-1
    compute_ktile(smem + cb * 32768, abase, bbase, acc);
#undef STAGE

    // epilogue: weighted atomic scatter-add (each out element gets exactly 2 adds)
    const int col0 = band * BN + wn * 64 + r16;
    #pragma unroll
    for (int mf = 0; mf < 8; ++mf) {
        const int rbase = wm * 128 + mf * 16 + c16 * 4;
        #pragma unroll
        for (int i = 0; i < 4; ++i) {
            int rl = rbase + i;
            if (rl < nrows) {
                int slot = wsi[WS_ROW_IDS + rstart + rl];
                float wt = topk_weight[slot];
                float* orow = Out + (size_t)(slot >> 1) * HDIM + col0;
                #pragma unroll
                for (int nf = 0; nf < 4; ++nf)
                    atomicAdd(orow + nf * 16, acc[mf][nf][i] * wt);
            }
        }
    }
}

extern "C" void kernel_launch(void* const* d_in, const int* in_sizes, int n_in,
                              void* d_out, int out_size, void* d_ws, size_t ws_size,
                              hipStream_t stream) {
    const float* X   = (const float*)d_in[0];
    const float* W   = (const float*)d_in[1];
    const float* wgt = (const float*)d_in[2];
    const int*   ids = (const int*)d_in[3];
    float* Out = (float*)d_out;
    int*   wsi = (int*)d_ws;
    unsigned char* apack = (unsigned char*)d_ws + WS_APACK_OFF;
    unsigned char* wb    = (unsigned char*)d_ws + WS_WB_OFF;

    hipMemsetAsync(d_out, 0, (size_t)out_size * sizeof(float), stream);
    routing_kernel<<<1, 256, 0, stream>>>(ids, wsi);
    pack_w_kernel<<<(NEXP * NKT * HDIM) / 256, 256, 0, stream>>>(W, wb);
    dim3 agrid(MAX_TILES, NKT, 1);
    pack_a_kernel<<<agrid, 256, 0, stream>>>(X, wsi, apack);
    gemm_fast<<<NBLK, 512, 98304, stream>>>(apack, wb, wgt, wsi, Out);
}